// Round 1
// baseline (6000.691 us; speedup 1.0000x reference)
//
#include <hip/hip_runtime.h>

#define MUL 128
#define DIN 9
#define BATCH 2048
#define NOUT 9          // total output rows per (b,c): 1+3+5
#define NP3 6
#define NP2 3
#define NTRI 165
#define NPAIR 45
#define WS3 (NOUT*NTRI*NP3)    // 8910
#define WS2 (NOUT*NPAIR*NP2)   // 1215
#define WS1 (NOUT*DIN)         // 81
#define WSTOT (WS3+WS2+WS1)    // 10206

// ---- compile-time tables for sorted pairs/triples ----
struct TriTab { unsigned char a[NTRI], b[NTRI], c[NTRI]; };
constexpr TriTab make_tri() {
  TriTab t{}; int q = 0;
  for (int a = 0; a < 9; a++) for (int b = a; b < 9; b++) for (int c = b; c < 9; c++) {
    t.a[q] = (unsigned char)a; t.b[q] = (unsigned char)b; t.c[q] = (unsigned char)c; q++;
  }
  return t;
}
constexpr TriTab TRI = make_tri();

struct PairTab { unsigned char a[NPAIR], b[NPAIR]; unsigned char idx[9][9]; };
constexpr PairTab make_pair() {
  PairTab t{}; int q = 0;
  for (int a = 0; a < 9; a++) for (int b = a; b < 9; b++) {
    t.a[q] = (unsigned char)a; t.b[q] = (unsigned char)b;
    t.idx[a][b] = (unsigned char)q; t.idx[b][a] = (unsigned char)q; q++;
  }
  return t;
}
constexpr PairTab PAIR = make_pair();

// ---- preprocessing: symmetrize U tensors into d_ws ----
// layout (floats): [0,WS3): o*(165*6)+q*6+k ; [WS3,WS3+WS2): o*(45*3)+q*3+k ; then o*9+i
__global__ void prep_kernel(const float* __restrict__ U30, const float* __restrict__ U20, const float* __restrict__ U10,
                            const float* __restrict__ U31, const float* __restrict__ U21, const float* __restrict__ U11,
                            const float* __restrict__ U32, const float* __restrict__ U22, const float* __restrict__ U12,
                            float* __restrict__ ws) {
  int t = blockIdx.x * blockDim.x + threadIdx.x;
  if (t >= WSTOT) return;
  const float* U3[3] = {U30, U31, U32};
  const float* U2[3] = {U20, U21, U22};
  const float* U1[3] = {U10, U11, U12};
  if (t < WS3) {
    int o = t / (NTRI * NP3); int r = t % (NTRI * NP3); int q = r / NP3; int k = r % NP3;
    int irrep = (o > 0) + (o > 3); int lo = o - (irrep == 1 ? 1 : (irrep == 2 ? 4 : 0));
    int a = 0, b = 0, cc = 0;
    { int idx = 0; bool done = false;
      for (int A = 0; A < 9 && !done; A++) for (int B = A; B < 9 && !done; B++) for (int C = B; C < 9 && !done; C++) {
        if (idx == q) { a = A; b = B; cc = C; done = true; } idx++; } }
    int pm[6][3] = {{a,b,cc},{a,cc,b},{b,a,cc},{b,cc,a},{cc,a,b},{cc,b,a}};
    float val = 0.f;
    for (int p = 0; p < 6; p++) {
      bool dup = false;
      for (int rr = 0; rr < p; rr++)
        if (pm[rr][0] == pm[p][0] && pm[rr][1] == pm[p][1] && pm[rr][2] == pm[p][2]) dup = true;
      if (dup) continue;
      val += U3[irrep][(((lo * 9 + pm[p][0]) * 9 + pm[p][1]) * 9 + pm[p][2]) * NP3 + k];
    }
    ws[t] = val;
  } else if (t < WS3 + WS2) {
    int t2 = t - WS3;
    int o = t2 / (NPAIR * NP2); int r = t2 % (NPAIR * NP2); int q = r / NP2; int k = r % NP2;
    int irrep = (o > 0) + (o > 3); int lo = o - (irrep == 1 ? 1 : (irrep == 2 ? 4 : 0));
    int a = 0, b = 0;
    { int idx = 0; bool done = false;
      for (int A = 0; A < 9 && !done; A++) for (int B = A; B < 9 && !done; B++) {
        if (idx == q) { a = A; b = B; done = true; } idx++; } }
    float val = U2[irrep][((lo * 9 + a) * 9 + b) * NP2 + k];
    if (a != b) val += U2[irrep][((lo * 9 + b) * 9 + a) * NP2 + k];
    ws[t] = val;
  } else {
    int t1 = t - WS3 - WS2;
    int o = t1 / DIN; int i = t1 % DIN;
    int irrep = (o > 0) + (o > 3); int lo = o - (irrep == 1 ? 1 : (irrep == 2 ? 4 : 0));
    ws[t] = U1[irrep][lo * 9 + i];
  }
}

// ---- main kernel: one lane per (b,c) pair ----
__global__ __launch_bounds__(256) void symcon_kernel(const float* __restrict__ x,
                                                     const int* __restrict__ indices,
                                                     const float* __restrict__ weight,
                                                     const float* __restrict__ ws,
                                                     float* __restrict__ out) {
  __shared__ float lds[WSTOT];
  for (int i = threadIdx.x; i < WSTOT; i += 256) lds[i] = ws[i];
  __syncthreads();

  int g = blockIdx.x * 256 + threadIdx.x;   // g = b*128 + c
  int b = g >> 7;
  int c = g & 127;

  const float* xp = x + (size_t)g * DIN;
  float xx[DIN];
#pragma unroll
  for (int i = 0; i < DIN; i++) xx[i] = xp[i];

  float pr[NPAIR];
#pragma unroll
  for (int q = 0; q < NPAIR; q++) pr[q] = xx[PAIR.a[q]] * xx[PAIR.b[q]];

  int e = indices[b];
  const float* wbase = weight + ((size_t)e * 30) * MUL + c;
  float* orow = out + (size_t)b * (MUL * NOUT);

#pragma unroll 1
  for (int o = 0; o < NOUT; o++) {
    int irrep = (o > 0) + (o > 3);

    const float* u3 = &lds[o * (NTRI * NP3)];
    float a3[NP3] = {0.f, 0.f, 0.f, 0.f, 0.f, 0.f};
#pragma unroll
    for (int q = 0; q < NTRI; q++) {
      float m = pr[PAIR.idx[TRI.a[q]][TRI.b[q]]] * xx[TRI.c[q]];
#pragma unroll
      for (int k = 0; k < NP3; k++) a3[k] = fmaf(u3[q * NP3 + k], m, a3[k]);
    }

    const float* u2 = &lds[WS3 + o * (NPAIR * NP2)];
    float a2[NP2] = {0.f, 0.f, 0.f};
#pragma unroll
    for (int q = 0; q < NPAIR; q++) {
#pragma unroll
      for (int k = 0; k < NP2; k++) a2[k] = fmaf(u2[q * NP2 + k], pr[q], a2[k]);
    }

    const float* u1 = &lds[WS3 + WS2 + o * DIN];
    float a1 = 0.f;
#pragma unroll
    for (int q = 0; q < DIN; q++) a1 = fmaf(u1[q], xx[q], a1);

    const float* wp = wbase + (size_t)irrep * 10 * MUL;
    float r = 0.f;
#pragma unroll
    for (int k = 0; k < NP3; k++) r = fmaf(a3[k], wp[k * MUL], r);
#pragma unroll
    for (int k = 0; k < NP2; k++) r = fmaf(a2[k], wp[(NP3 + k) * MUL], r);
    r = fmaf(a1, wp[9 * MUL], r);

    int col;
    if (o == 0)      col = c;
    else if (o < 4)  col = 128 + c * 3 + (o - 1);
    else             col = 512 + c * 5 + (o - 4);
    orow[col] = r;
  }
}

extern "C" void kernel_launch(void* const* d_in, const int* in_sizes, int n_in,
                              void* d_out, int out_size, void* d_ws, size_t ws_size,
                              hipStream_t stream) {
  const float* x   = (const float*)d_in[0];
  const int*   idx = (const int*)d_in[1];
  const float* w   = (const float*)d_in[2];
  const float* U30 = (const float*)d_in[3];
  const float* U20 = (const float*)d_in[4];
  const float* U10 = (const float*)d_in[5];
  const float* U31 = (const float*)d_in[6];
  const float* U21 = (const float*)d_in[7];
  const float* U11 = (const float*)d_in[8];
  const float* U32 = (const float*)d_in[9];
  const float* U22 = (const float*)d_in[10];
  const float* U12 = (const float*)d_in[11];
  float* ws  = (float*)d_ws;
  float* out = (float*)d_out;

  prep_kernel<<<(WSTOT + 255) / 256, 256, 0, stream>>>(U30, U20, U10, U31, U21, U11, U32, U22, U12, ws);
  symcon_kernel<<<(BATCH * MUL) / 256, 256, 0, stream>>>(x, idx, w, ws, out);
}

// Round 2
// 110.264 us; speedup vs baseline: 54.4211x; 54.4211x over previous
//
#include <hip/hip_runtime.h>

#define MUL 128
#define DIN 9
#define BATCH 2048
#define NOUT 9
#define NP3 6
#define NP2 3
#define NTRI 165
#define NPAIR 45

// ws layout (float elements)
#define U3P_STRIDE 56
#define U3P_SZ (NTRI * U3P_STRIDE)       // 9240  : [q][o*6+k], pads 54,55 = 0
#define U2P_OFF U3P_SZ
#define U2P_STRIDE 28
#define U2P_SZ (NPAIR * U2P_STRIDE)      // 1260  : [p][o*3+k], pad 27 = 0
#define U1P_OFF (U2P_OFF + U2P_SZ)       // 10500
#define U1P_SZ (DIN * 12)                // 108   : [i][o], pads 9..11 = 0
#define TRI_OFF (U1P_OFF + U1P_SZ)       // 10608 : packed uint a|b<<8|c<<16
#define PAIR_OFF (TRI_OFF + NTRI)        // 10773 : packed uint a|b<<8
#define WS_TOTAL (PAIR_OFF + NPAIR)      // 10818 floats = 43.3 KB

// ---- prep: symmetrize U tensors into scalar-load-friendly layout ----
__global__ void prep_kernel(const float* __restrict__ U30, const float* __restrict__ U20, const float* __restrict__ U10,
                            const float* __restrict__ U31, const float* __restrict__ U21, const float* __restrict__ U11,
                            const float* __restrict__ U32, const float* __restrict__ U22, const float* __restrict__ U12,
                            float* __restrict__ ws) {
  int t = blockIdx.x * blockDim.x + threadIdx.x;
  if (t >= WS_TOTAL) return;
  const float* U3[3] = {U30, U31, U32};
  const float* U2[3] = {U20, U21, U22};
  const float* U1[3] = {U10, U11, U12};

  if (t < U3P_SZ) {
    int q = t / U3P_STRIDE, n = t % U3P_STRIDE;
    if (n >= 54) { ws[t] = 0.f; return; }
    int o = n / 6, k = n % 6;
    int irrep = (o > 0) + (o > 3); int lo = o - (irrep == 1 ? 1 : (irrep == 2 ? 4 : 0));
    int a = 0, b = 0, cc = 0;
    { int idx = 0; bool done = false;
      for (int A = 0; A < 9 && !done; A++) for (int B = A; B < 9 && !done; B++) for (int C = B; C < 9 && !done; C++) {
        if (idx == q) { a = A; b = B; cc = C; done = true; } idx++; } }
    int pm[6][3] = {{a,b,cc},{a,cc,b},{b,a,cc},{b,cc,a},{cc,a,b},{cc,b,a}};
    float val = 0.f;
    for (int p = 0; p < 6; p++) {
      bool dup = false;
      for (int rr = 0; rr < p; rr++)
        if (pm[rr][0] == pm[p][0] && pm[rr][1] == pm[p][1] && pm[rr][2] == pm[p][2]) dup = true;
      if (dup) continue;
      val += U3[irrep][(((lo * 9 + pm[p][0]) * 9 + pm[p][1]) * 9 + pm[p][2]) * NP3 + k];
    }
    ws[t] = val;
  } else if (t < U1P_OFF) {
    int t2 = t - U2P_OFF;
    int p = t2 / U2P_STRIDE, n = t2 % U2P_STRIDE;
    if (n >= 27) { ws[t] = 0.f; return; }
    int o = n / 3, k = n % 3;
    int irrep = (o > 0) + (o > 3); int lo = o - (irrep == 1 ? 1 : (irrep == 2 ? 4 : 0));
    int a = 0, b = 0;
    { int idx = 0; bool done = false;
      for (int A = 0; A < 9 && !done; A++) for (int B = A; B < 9 && !done; B++) {
        if (idx == p) { a = A; b = B; done = true; } idx++; } }
    float val = U2[irrep][((lo * 9 + a) * 9 + b) * NP2 + k];
    if (a != b) val += U2[irrep][((lo * 9 + b) * 9 + a) * NP2 + k];
    ws[t] = val;
  } else if (t < TRI_OFF) {
    int t1 = t - U1P_OFF;
    int i = t1 / 12, o = t1 % 12;
    if (o >= 9) { ws[t] = 0.f; return; }
    int irrep = (o > 0) + (o > 3); int lo = o - (irrep == 1 ? 1 : (irrep == 2 ? 4 : 0));
    ws[t] = U1[irrep][lo * 9 + i];
  } else if (t < PAIR_OFF) {
    int q = t - TRI_OFF;
    int a = 0, b = 0, cc = 0;
    { int idx = 0; bool done = false;
      for (int A = 0; A < 9 && !done; A++) for (int B = A; B < 9 && !done; B++) for (int C = B; C < 9 && !done; C++) {
        if (idx == q) { a = A; b = B; cc = C; done = true; } idx++; } }
    ((unsigned*)ws)[t] = (unsigned)a | ((unsigned)b << 8) | ((unsigned)cc << 16);
  } else {
    int p = t - PAIR_OFF;
    int a = 0, b = 0;
    { int idx = 0; bool done = false;
      for (int A = 0; A < 9 && !done; A++) for (int B = A; B < 9 && !done; B++) {
        if (idx == p) { a = A; b = B; done = true; } idx++; } }
    ((unsigned*)ws)[t] = (unsigned)a | ((unsigned)b << 8);
  }
}

// ---- main kernel: one lane per (b,c); runtime monomial loop, scalar U loads ----
__global__ __launch_bounds__(256) void symcon_kernel(const float* __restrict__ x,
                                                     const int* __restrict__ indices,
                                                     const float* __restrict__ weight,
                                                     const float* __restrict__ ws,
                                                     float* __restrict__ out) {
  __shared__ float xl[256 * 13];   // per-lane x row, stride 13 (2-way bank alias = free)
  int tid = threadIdx.x;
  int g = blockIdx.x * 256 + tid;  // g = b*128 + c
  int b = g >> 7;
  int c = g & 127;

  const float* xp = x + (size_t)g * DIN;
  float* xrow = &xl[tid * 13];
  float xx[DIN];
#pragma unroll
  for (int i = 0; i < DIN; i++) { xx[i] = xp[i]; xrow[i] = xx[i]; }
  // no __syncthreads needed: each lane reads only its own LDS row

  float a3[54], a2[27], a1[9];
#pragma unroll
  for (int n = 0; n < 54; n++) a3[n] = 0.f;
#pragma unroll
  for (int n = 0; n < 27; n++) a2[n] = 0.f;
#pragma unroll
  for (int n = 0; n < 9; n++) a1[n] = 0.f;

  const unsigned* tri  = (const unsigned*)(ws + TRI_OFF);
  const unsigned* pair = (const unsigned*)(ws + PAIR_OFF);

  // degree-3: 165 symmetric triples
#pragma unroll 3
  for (int q = 0; q < NTRI; q++) {
    int qq = __builtin_amdgcn_readfirstlane(q);
    unsigned tp = tri[qq];                       // scalar load
    float xa = xrow[tp & 255u];
    float xb = xrow[(tp >> 8) & 255u];
    float xc = xrow[(tp >> 16) & 255u];
    float m = xa * xb * xc;
    const float* u = ws + qq * U3P_STRIDE;       // uniform -> s_load_dwordx16
#pragma unroll
    for (int n = 0; n < 54; n++) a3[n] = fmaf(u[n], m, a3[n]);
  }

  // degree-2: 45 symmetric pairs
#pragma unroll 3
  for (int p = 0; p < NPAIR; p++) {
    int pp = __builtin_amdgcn_readfirstlane(p);
    unsigned pk = pair[pp];
    float m = xrow[pk & 255u] * xrow[(pk >> 8) & 255u];
    const float* u = ws + U2P_OFF + pp * U2P_STRIDE;
#pragma unroll
    for (int n = 0; n < 27; n++) a2[n] = fmaf(u[n], m, a2[n]);
  }

  // degree-1: compile-time indices
#pragma unroll
  for (int i = 0; i < DIN; i++) {
    const float* u = ws + U1P_OFF + i * 12;
#pragma unroll
    for (int o = 0; o < 9; o++) a1[o] = fmaf(u[o], xx[i], a1[o]);
  }

  // combine with gathered per-element weights
  int e = indices[b];
  const float* wbase = weight + (size_t)e * 30 * MUL + c;
  float* orow = out + (size_t)b * (MUL * NOUT);

#pragma unroll
  for (int o = 0; o < 9; o++) {
    int irrep = (o > 0) + (o > 3);
    const float* wp = wbase + irrep * 10 * MUL;
    float r = 0.f;
#pragma unroll
    for (int k = 0; k < 6; k++) r = fmaf(a3[o * 6 + k], wp[k * MUL], r);
#pragma unroll
    for (int k = 0; k < 3; k++) r = fmaf(a2[o * 3 + k], wp[(6 + k) * MUL], r);
    r = fmaf(a1[o], wp[9 * MUL], r);

    int col;
    if (o == 0)      col = c;
    else if (o < 4)  col = 128 + c * 3 + (o - 1);
    else             col = 512 + c * 5 + (o - 4);
    orow[col] = r;
  }
}

extern "C" void kernel_launch(void* const* d_in, const int* in_sizes, int n_in,
                              void* d_out, int out_size, void* d_ws, size_t ws_size,
                              hipStream_t stream) {
  const float* x   = (const float*)d_in[0];
  const int*   idx = (const int*)d_in[1];
  const float* w   = (const float*)d_in[2];
  const float* U30 = (const float*)d_in[3];
  const float* U20 = (const float*)d_in[4];
  const float* U10 = (const float*)d_in[5];
  const float* U31 = (const float*)d_in[6];
  const float* U21 = (const float*)d_in[7];
  const float* U11 = (const float*)d_in[8];
  const float* U32 = (const float*)d_in[9];
  const float* U22 = (const float*)d_in[10];
  const float* U12 = (const float*)d_in[11];
  float* ws  = (float*)d_ws;
  float* out = (float*)d_out;

  prep_kernel<<<(WS_TOTAL + 255) / 256, 256, 0, stream>>>(U30, U20, U10, U31, U21, U11, U32, U22, U12, ws);
  symcon_kernel<<<(BATCH * MUL) / 256, 256, 0, stream>>>(x, idx, w, ws, out);
}